// Round 19
// baseline (977.608 us; speedup 1.0000x reference)
//
#include <hip/hip_runtime.h>
#include <stdint.h>

typedef __attribute__((ext_vector_type(8))) short short8;
typedef __attribute__((ext_vector_type(4))) float floatx4;
typedef __attribute__((ext_vector_type(16))) float floatx16;

__device__ __forceinline__ float bf2f(unsigned short h) {
  union { unsigned int u; float f; } v; v.u = ((unsigned int)h) << 16; return v.f;
}
__device__ __forceinline__ unsigned short f2bf(float f) {
  union { float f; unsigned int u; } v; v.f = f;
  unsigned int r = v.u + 0x7fffu + ((v.u >> 16) & 1u);
  return (unsigned short)(r >> 16);
}

__device__ __forceinline__ void gll16(const void* g, void* l) {
  __builtin_amdgcn_global_load_lds((const __attribute__((address_space(1))) unsigned int*)g,
                                   (__attribute__((address_space(3))) unsigned int*)l, 16, 0, 0);
}

// XCD-aware block swizzle (T1): XCD k gets a contiguous run of work-ids. Bijective when nwg%8==0.
__device__ __forceinline__ int xcd_swz_id() {
  const int nx = gridDim.x;
  const int nwg = nx * gridDim.y;
  const int orig = blockIdx.y * nx + blockIdx.x;
  if ((nwg & 7) == 0) {
    const int q = nwg >> 3;
    return (orig & 7) * q + (orig >> 3);
  }
  return orig;
}

// DPP row_ror:K — VALU pipe.
template <int K>
__device__ __forceinline__ float rorf(float x) {
  return __int_as_float(__builtin_amdgcn_update_dpp(0, __float_as_int(x), 0x120 + K, 0xF, 0xF, false));
}
__device__ __forceinline__ float grpsum16(float v) {
  v += rorf<1>(v); v += rorf<2>(v); v += rorf<4>(v); v += rorf<8>(v);
  return v;
}
__device__ __forceinline__ float swz16(float x) {
  return __int_as_float(__builtin_amdgcn_ds_swizzle(__float_as_int(x), 0x401F));
}

// ------------- weight transpose+convert: in f32 (K,N) -> out bf16 (N,K) -------------
__global__ __launch_bounds__(256) void transpose_kern(const float* __restrict__ in,
                                                      unsigned short* __restrict__ out,
                                                      int K, int N) {
  __shared__ float tile[32][33];
  const int tx = threadIdx.x & 31, ty = threadIdx.x >> 5;
  const int n0 = blockIdx.x * 32, k0 = blockIdx.y * 32;
#pragma unroll
  for (int i = 0; i < 4; ++i)
    tile[ty + 8 * i][tx] = in[(size_t)(k0 + ty + 8 * i) * N + n0 + tx];
  __syncthreads();
#pragma unroll
  for (int i = 0; i < 4; ++i)
    out[(size_t)(n0 + ty + 8 * i) * K + k0 + tx] = f2bf(tile[tx][ty + 8 * i]);
}

// ------------- LayerNorm (f32 or bf16 in) -> bf16 (+ optional roll/window scatter) -------------
template <int BF16IN>
__global__ __launch_bounds__(256) void ln_kern(const void* __restrict__ xv,
                                               const float* __restrict__ g,
                                               const float* __restrict__ b,
                                               unsigned short* __restrict__ out,
                                               int tokenBase, int scatter) {
  const int t = tokenBase + blockIdx.x;
  const int c = threadIdx.x * 2;
  float x0, x1;
  if (BF16IN) {
    const unsigned int u = *(const unsigned int*)((const unsigned short*)xv + (size_t)t * 512 + c);
    x0 = bf2f((unsigned short)(u & 0xffffu)); x1 = bf2f((unsigned short)(u >> 16));
  } else {
    const float* xr = (const float*)xv + (size_t)t * 512;
    x0 = xr[c]; x1 = xr[c + 1];
  }
  float s = x0 + x1, s2 = x0 * x0 + x1 * x1;
#pragma unroll
  for (int off = 32; off; off >>= 1) {
    s += __shfl_xor(s, off, 64);
    s2 += __shfl_xor(s2, off, 64);
  }
  __shared__ float red[2][4];
  const int l = threadIdx.x & 63, wv = threadIdx.x >> 6;
  if (l == 0) { red[0][wv] = s; red[1][wv] = s2; }
  __syncthreads();
  s = red[0][0] + red[0][1] + red[0][2] + red[0][3];
  s2 = red[1][0] + red[1][1] + red[1][2] + red[1][3];
  const float mean = s * (1.0f / 512.0f);
  const float var = s2 * (1.0f / 512.0f) - mean * mean;
  const float rstd = rsqrtf(var + 1e-5f);
  const float y0 = (x0 - mean) * rstd * g[c] + b[c];
  const float y1 = (x1 - mean) * rstd * g[c + 1] + b[c + 1];
  int orow;
  if (scatter) {
    const int bb = t >> 12, rem = t & 4095, h = rem >> 6, w = rem & 63;
    const int hp = (h + 60) & 63, wp = (w + 60) & 63;
    const int wh = hp >> 3, i = hp & 7, ww = wp >> 3, j = wp & 7;
    const int rg = ((bb << 6) + (wh << 3) + ww) * 64 + (i << 3) + j;
    orow = rg - tokenBase;
  } else {
    orow = blockIdx.x;
  }
  const unsigned int o = (unsigned int)f2bf(y0) | ((unsigned int)f2bf(y1) << 16);
  *(unsigned int*)(out + (size_t)orow * 512 + c) = o;
}

// ------------- 128² GEMM (fallback path): counted-vmcnt dbuf (no sched pins) -------------
template <int EPI>
__global__ __launch_bounds__(256) void gemm_bt(const unsigned short* __restrict__ A,
                                               const unsigned short* __restrict__ Bt,
                                               const float* __restrict__ bias,
                                               void* __restrict__ outv,
                                               const void* __restrict__ resv,
                                               int M, int N, int K, int rowBase) {
  __shared__ unsigned short As[2][128][64];
  __shared__ unsigned short Bs[2][128][64];
  const int tid = threadIdx.x;
  const int l = tid & 63, wv = tid >> 6;
  const int wm = wv >> 1, wn = wv & 1;
  const int id = xcd_swz_id();
  const int bm = (id / gridDim.x) * 128, bn = (id % gridDim.x) * 128;

  floatx4 acc[4][4];
#pragma unroll
  for (int i = 0; i < 4; ++i)
#pragma unroll
    for (int j = 0; j < 4; ++j) acc[i][j] = {0.0f, 0.0f, 0.0f, 0.0f};

  const int srow = l >> 3;
  const int sslot = ((l & 7) ^ (l >> 3)) * 8;
  const unsigned short* Abase = A + (size_t)(bm + srow) * K + sslot;
  const unsigned short* Bbase = Bt + (size_t)(bn + srow) * K + sslot;

#define STAGE(bb, k0)                                                        \
  {                                                                          \
    _Pragma("unroll")                                                        \
    for (int tt = 0; tt < 4; ++tt) {                                         \
      const int r = wv * 32 + tt * 8;                                        \
      gll16(Abase + (size_t)r * K + (k0), &As[bb][r][0]);                    \
      gll16(Bbase + (size_t)r * K + (k0), &Bs[bb][r][0]);                    \
    }                                                                        \
  }

  STAGE(0, 0);   // 8 loads/thread in flight

  const int ntl = K >> 6;
  int cur = 0;
#pragma unroll 1
  for (int t = 0; t < ntl; ++t) {
    if (t + 1 < ntl) {
      STAGE(cur ^ 1, (t + 1) * 64);                      // +8 loads (tile t+1)
      asm volatile("s_waitcnt vmcnt(8)" ::: "memory");   // wait only tile t's loads
    } else {
      asm volatile("s_waitcnt vmcnt(0)" ::: "memory");
    }
    __builtin_amdgcn_s_barrier();                        // cur tile resident (all waves)
    asm volatile("" ::: "memory");                       // compiler fence only (no sched pin)
    __builtin_amdgcn_s_setprio(1);
#pragma unroll
    for (int kh = 0; kh < 2; ++kh) {
      const int rslot = ((kh * 4 + (l >> 4)) ^ (l & 7)) * 8;
      short8 af[4], bfr[4];
#pragma unroll
      for (int mt = 0; mt < 4; ++mt)
        af[mt] = *(const short8*)&As[cur][wm * 64 + mt * 16 + (l & 15)][rslot];
#pragma unroll
      for (int nt2 = 0; nt2 < 4; ++nt2)
        bfr[nt2] = *(const short8*)&Bs[cur][wn * 64 + nt2 * 16 + (l & 15)][rslot];
#pragma unroll
      for (int mt = 0; mt < 4; ++mt)
#pragma unroll
        for (int nt2 = 0; nt2 < 4; ++nt2)
          acc[mt][nt2] = __builtin_amdgcn_mfma_f32_16x16x32_bf16(af[mt], bfr[nt2], acc[mt][nt2], 0, 0, 0);
    }
    __builtin_amdgcn_s_setprio(0);
    asm volatile("" ::: "memory");
    __builtin_amdgcn_s_barrier();                        // all reads of cur done -> overwrite safe
    cur ^= 1;
  }
#undef STAGE

#pragma unroll
  for (int mt = 0; mt < 4; ++mt) {
#pragma unroll
    for (int nt2 = 0; nt2 < 4; ++nt2) {
      const int gcol = bn + wn * 64 + nt2 * 16 + (l & 15);
      const float bv = bias[gcol];
#pragma unroll
      for (int r = 0; r < 4; ++r) {
        const int grow = bm + wm * 64 + mt * 16 + (l >> 4) * 4 + r;
        float v = acc[mt][nt2][r] + bv;
        if (EPI == 1) {
          const float t2 = v * (1.5957691216057308f + 0.071354816222f * v * v);
          v = v * (1.0f / (1.0f + __expf(-t2)));
        }
        if (EPI == 2) {
          const int rg = rowBase + grow;
          const int bw = rg >> 6, n = rg & 63;
          const int bb = bw >> 6, wi = bw & 63;
          const int i = n >> 3, j = n & 7;
          const int hp = ((wi >> 3) << 3) + i;
          const int wp = ((wi & 7) << 3) + j;
          const int h = (hp + 4) & 63, w = (wp + 4) & 63;
          const size_t t = (size_t)((bb << 12) + (h << 6) + w);
          ((unsigned short*)outv)[t * 512 + gcol] = f2bf(v + ((const float*)resv)[t * 512 + gcol]);
        } else if (EPI == 3) {
          ((float*)outv)[(size_t)grow * 512 + gcol] =
              v + bf2f(((const unsigned short*)resv)[(size_t)grow * 512 + gcol]);
        } else {
          ((unsigned short*)outv)[(size_t)grow * (size_t)N + gcol] = f2bf(v);
        }
      }
    }
  }
}

// ------------- 256² GEMM, 32x32x16 MFMA (8 waves): counted-vmcnt dbuf (no sched pins) -------------
// C/D layout (HW-verified): col = lane&31, row = (reg&3) + 8*(reg>>2) + 4*(lane>>5)
template <int EPI>
__global__ __launch_bounds__(512) void gemm256(const unsigned short* __restrict__ A,
                                               const unsigned short* __restrict__ Bt,
                                               const float* __restrict__ bias,
                                               void* __restrict__ outv,
                                               const void* __restrict__ resv,
                                               int M, int N, int K, int rowBase) {
  __shared__ unsigned short As[2][256][64];
  __shared__ unsigned short Bs[2][256][64];
  const int tid = threadIdx.x;
  const int l = tid & 63, wid = tid >> 6;
  const int wm = wid >> 2, wn = wid & 3;
  const int id = xcd_swz_id();
  const int bm = (id / gridDim.x) * 256, bn = (id % gridDim.x) * 256;

  floatx16 acc[4][2];
#pragma unroll
  for (int i = 0; i < 4; ++i)
#pragma unroll
    for (int j = 0; j < 2; ++j)
#pragma unroll
      for (int r = 0; r < 16; ++r) acc[i][j][r] = 0.0f;

  const int srow = tid >> 3;
  const int sslot = ((tid & 7) ^ (srow & 7)) * 8;
  const unsigned short* Ab = A + (size_t)(bm + srow) * K + sslot;
  const unsigned short* Bb = Bt + (size_t)(bn + srow) * K + sslot;
  const int ldsbase = wid * 8;

#define STG256(bb, k0)                                                          \
  {                                                                             \
    _Pragma("unroll")                                                           \
    for (int tt = 0; tt < 4; ++tt) {                                            \
      gll16(Ab + (size_t)(tt * 64) * K + (k0), &As[bb][tt * 64 + ldsbase][0]);  \
      gll16(Bb + (size_t)(tt * 64) * K + (k0), &Bs[bb][tt * 64 + ldsbase][0]);  \
    }                                                                           \
  }

  STG256(0, 0);   // 8 loads/thread in flight

  const int ntl = K >> 6;
  int cur = 0;
#pragma unroll 1
  for (int t = 0; t < ntl; ++t) {
    if (t + 1 < ntl) {
      STG256(cur ^ 1, (t + 1) * 64);
      asm volatile("s_waitcnt vmcnt(8)" ::: "memory");
    } else {
      asm volatile("s_waitcnt vmcnt(0)" ::: "memory");
    }
    __builtin_amdgcn_s_barrier();
    asm volatile("" ::: "memory");
    __builtin_amdgcn_s_setprio(1);
#pragma unroll
    for (int ks = 0; ks < 4; ++ks) {            // 4 k-steps of K=16
      const int rslot = ((ks * 2 + (l >> 5)) ^ (l & 7)) * 8;
      short8 af[4], bfr[2];
#pragma unroll
      for (int mt = 0; mt < 4; ++mt)
        af[mt] = *(const short8*)&As[cur][wm * 128 + mt * 32 + (l & 31)][rslot];
#pragma unroll
      for (int nt2 = 0; nt2 < 2; ++nt2)
        bfr[nt2] = *(const short8*)&Bs[cur][wn * 64 + nt2 * 32 + (l & 31)][rslot];
#pragma unroll
      for (int mt = 0; mt < 4; ++mt)
#pragma unroll
        for (int nt2 = 0; nt2 < 2; ++nt2)
          acc[mt][nt2] = __builtin_amdgcn_mfma_f32_32x32x16_bf16(af[mt], bfr[nt2], acc[mt][nt2], 0, 0, 0);
    }
    __builtin_amdgcn_s_setprio(0);
    asm volatile("" ::: "memory");
    __builtin_amdgcn_s_barrier();
    cur ^= 1;
  }
#undef STG256

#pragma unroll
  for (int mt = 0; mt < 4; ++mt) {
#pragma unroll
    for (int nt2 = 0; nt2 < 2; ++nt2) {
      const int gcol = bn + wn * 64 + nt2 * 32 + (l & 31);
      const float bv = bias[gcol];
#pragma unroll
      for (int r = 0; r < 16; ++r) {
        const int grow = bm + wm * 128 + mt * 32 + (r & 3) + 8 * (r >> 2) + 4 * (l >> 5);
        float v = acc[mt][nt2][r] + bv;
        if (EPI == 1) {
          const float t2 = v * (1.5957691216057308f + 0.071354816222f * v * v);
          v = v * (1.0f / (1.0f + __expf(-t2)));
        }
        if (EPI == 2) {
          const int rg = rowBase + grow;
          const int bw = rg >> 6, n = rg & 63;
          const int bb = bw >> 6, wi = bw & 63;
          const int i = n >> 3, j = n & 7;
          const int hp = ((wi >> 3) << 3) + i;
          const int wp = ((wi & 7) << 3) + j;
          const int h = (hp + 4) & 63, w = (wp + 4) & 63;
          const size_t t = (size_t)((bb << 12) + (h << 6) + w);
          ((unsigned short*)outv)[t * 512 + gcol] = f2bf(v + ((const float*)resv)[t * 512 + gcol]);
        } else if (EPI == 3) {
          ((float*)outv)[(size_t)grow * 512 + gcol] =
              v + bf2f(((const unsigned short*)resv)[(size_t)grow * 512 + gcol]);
        } else {
          ((unsigned short*)outv)[(size_t)grow * (size_t)N + gcol] = f2bf(v);
        }
      }
    }
  }
}

// ------------- attention per (window, head), 8 waves: QK^T + bias, top-48 radix, P@V ----
__global__ __launch_bounds__(512) void attn_kern(const unsigned short* __restrict__ qkv,
                                                 const float* __restrict__ relb,
                                                 unsigned short* __restrict__ attnout) {
  __shared__ float Ss[64][66];
  __shared__ unsigned short VT[32][66];
  __shared__ float biasL[240];

  const int u = blockIdx.x;
  const int bwl = u >> 4, head = u & 15;
  const int tid = threadIdx.x;
  const int l = tid & 63, w = tid >> 6;   // 8 waves

  if (tid < 256) {
    const int row = tid >> 2, d0 = (tid & 3) * 8;
    short8 v8 = *(const short8*)(qkv + (size_t)(bwl * 64 + row) * 1536 + 1024 + head * 32 + d0);
#pragma unroll
    for (int j = 0; j < 8; ++j) VT[d0 + j][row] = (unsigned short)v8[j];
  } else if (tid < 256 + 225) {
    biasL[tid - 256] = relb[(tid - 256) * 16 + head];
  }
  __syncthreads();

  {
    const int rb = w >> 1, ch = w & 1;
    short8 a = *(const short8*)(qkv + (size_t)(bwl * 64 + rb * 16 + (l & 15)) * 1536 +
                                head * 32 + (l >> 4) * 8);
    const int n0 = rb * 16 + (l >> 4) * 4;
    const int m0 = ch * 32 + (l & 15);
    const int ibase = ((n0 >> 3) - (m0 >> 3) + 7) * 15 + ((n0 & 7) - (m0 & 7) + 7);
#pragma unroll
    for (int nt2 = 0; nt2 < 2; ++nt2) {
      short8 bfr = *(const short8*)(qkv + (size_t)(bwl * 64 + ch * 32 + nt2 * 16 + (l & 15)) * 1536 +
                                    512 + head * 32 + (l >> 4) * 8);
      floatx4 z = {0.0f, 0.0f, 0.0f, 0.0f};
      floatx4 d = __builtin_amdgcn_mfma_f32_16x16x32_bf16(a, bfr, z, 0, 0, 0);
#pragma unroll
      for (int r = 0; r < 4; ++r)
        Ss[n0 + r][m0 + nt2 * 16] = fmaf(d[r], 0.17677669529663689f, biasL[ibase + r - 30 * nt2]);
    }
  }
  __syncthreads();

  // top-48 + softmax: wave w owns rows w*8..w*8+7 (ballot-radix threshold — proven fastest form)
  float* srow_base = &Ss[w * 8][0];
#pragma unroll 1
  for (int rr = 0; rr < 8; ++rr) {
    const float own = srow_base[rr * 66 + l];
    const unsigned int uo = __float_as_uint(own);
    const unsigned int mapped = uo ^ ((unsigned int)((int)uo >> 31) | 0x80000000u);
    unsigned int p = 0;
#pragma unroll
    for (int b = 31; b >= 0; --b) {
      const unsigned int cand = p | (1u << b);
      const int c = __popcll(__ballot(mapped >= cand));
      if (c >= 48) {
        p = cand;
        if (c == 48) break;   // exactly 48 kept — threshold found
      }
    }
    const float tf = __uint_as_float((p & 0x80000000u) ? (p ^ 0x80000000u) : ~p);
    const float e = (mapped >= p) ? __expf(own - tf) : 0.0f;
    float zs = grpsum16(e);
    zs += swz16(zs);
    zs += __shfl_xor(zs, 32, 64);
    ((unsigned short*)(srow_base + rr * 66))[l] = f2bf(e * __builtin_amdgcn_rcpf(zs));
  }
  __syncthreads();

  {
    const int rb = w >> 1, cb = w & 1;
    floatx4 acc = {0.0f, 0.0f, 0.0f, 0.0f};
#pragma unroll
    for (int kh = 0; kh < 2; ++kh) {
      short8 pa = *(const short8*)((const unsigned short*)&Ss[rb * 16 + (l & 15)][0] +
                                   kh * 32 + (l >> 4) * 8);
      short8 vb = *(const short8*)&VT[cb * 16 + (l & 15)][kh * 32 + (l >> 4) * 8];
      acc = __builtin_amdgcn_mfma_f32_16x16x32_bf16(pa, vb, acc, 0, 0, 0);
    }
#pragma unroll
    for (int r = 0; r < 4; ++r) {
      const int n = rb * 16 + (l >> 4) * 4 + r;
      const int dcol = cb * 16 + (l & 15);
      attnout[(size_t)(bwl * 64 + n) * 512 + head * 32 + dcol] = f2bf(acc[r]);
    }
  }
}

// ---------------- launcher ----------------
extern "C" void kernel_launch(void* const* d_in, const int* in_sizes, int n_in,
                              void* d_out, int out_size, void* d_ws, size_t ws_size,
                              hipStream_t stream) {
  (void)in_sizes; (void)n_in; (void)out_size;
  const float* x      = (const float*)d_in[0];
  const float* n1g    = (const float*)d_in[1];
  const float* n1b    = (const float*)d_in[2];
  const float* qkv_w  = (const float*)d_in[3];
  const float* qkv_b  = (const float*)d_in[4];
  const float* relb   = (const float*)d_in[5];
  const float* proj_w = (const float*)d_in[6];
  const float* proj_b = (const float*)d_in[7];
  const float* n2g    = (const float*)d_in[8];
  const float* n2b    = (const float*)d_in[9];
  const float* fc1_w  = (const float*)d_in[10];
  const float* fc1_b  = (const float*)d_in[11];
  const float* fc2_w  = (const float*)d_in[12];
  const float* fc2_b  = (const float*)d_in[13];
  float* outp = (float*)d_out;

  unsigned short* qkvT  = (unsigned short*)d_ws;
  unsigned short* projT = qkvT + 1536 * 512;
  unsigned short* fc1T  = projT + 512 * 512;
  unsigned short* fc2T  = fc1T + 2048 * 512;
  const size_t wbytes = (size_t)(1536 * 512 + 512 * 512 + 2048 * 512 + 512 * 2048) * 2;
  unsigned short* x2bf = (unsigned short*)((char*)d_ws + wbytes);
  const size_t x2bytes = (size_t)65536 * 512 * 2;
  size_t rem = (ws_size > wbytes + x2bytes) ? ws_size - wbytes - x2bytes : 0;
  int R = (int)(rem / 5120);
  R = (R / 4096) * 4096;
  if (R > 65536) R = 65536;   // single-pass when ws permits (512 MiB does: 405 MB needed)
  if (R < 4096) R = 4096;
  const int nch = 65536 / R;
  unsigned short* bufA = x2bf + (size_t)65536 * 512;
  unsigned short* bufB = bufA + (size_t)R * 512;

  transpose_kern<<<dim3(1536 / 32, 512 / 32), 256, 0, stream>>>(qkv_w, qkvT, 512, 1536);
  transpose_kern<<<dim3(512 / 32, 512 / 32), 256, 0, stream>>>(proj_w, projT, 512, 512);
  transpose_kern<<<dim3(2048 / 32, 512 / 32), 256, 0, stream>>>(fc1_w, fc1T, 512, 2048);
  transpose_kern<<<dim3(512 / 32, 2048 / 32), 256, 0, stream>>>(fc2_w, fc2T, 2048, 512);

  for (int cb = 0; cb < nch; ++cb) {
    ln_kern<0><<<R, 256, 0, stream>>>(x, n1g, n1b, bufA, cb * R, 1);
    if ((R & 255) == 0) {
      gemm256<0><<<dim3(6, R / 256), 512, 0, stream>>>(bufA, qkvT, qkv_b, bufB, nullptr,
                                                       R, 1536, 512, 0);
    } else {
      gemm_bt<0><<<dim3(12, R / 128), 256, 0, stream>>>(bufA, qkvT, qkv_b, bufB, nullptr,
                                                        R, 1536, 512, 0);
    }
    attn_kern<<<(R / 64) * 16, 512, 0, stream>>>(bufB, relb, bufA);
    if ((R & 255) == 0) {
      gemm256<2><<<dim3(2, R / 256), 512, 0, stream>>>(bufA, projT, proj_b, x2bf, x,
                                                       R, 512, 512, cb * R);
    } else {
      gemm_bt<2><<<dim3(4, R / 128), 256, 0, stream>>>(bufA, projT, proj_b, x2bf, x,
                                                       R, 512, 512, cb * R);
    }
    ln_kern<1><<<R, 256, 0, stream>>>(x2bf, n2g, n2b, bufA, cb * R, 0);
    if ((R & 255) == 0) {
      gemm256<1><<<dim3(8, R / 256), 512, 0, stream>>>(bufA, fc1T, fc1_b, bufB, nullptr,
                                                       R, 2048, 512, 0);
      gemm256<3><<<dim3(2, R / 256), 512, 0, stream>>>(bufB, fc2T, fc2_b,
                                                       outp + (size_t)cb * R * 512,
                                                       x2bf + (size_t)cb * R * 512,
                                                       R, 512, 2048, 0);
    } else {
      gemm_bt<1><<<dim3(16, R / 128), 256, 0, stream>>>(bufA, fc1T, fc1_b, bufB, nullptr,
                                                        R, 2048, 512, 0);
      gemm_bt<3><<<dim3(4, R / 128), 256, 0, stream>>>(bufB, fc2T, fc2_b,
                                                       outp + (size_t)cb * R * 512,
                                                       x2bf + (size_t)cb * R * 512,
                                                       R, 512, 2048, 0);
    }
  }
}

// Round 20
// 884.907 us; speedup vs baseline: 1.1048x; 1.1048x over previous
//
#include <hip/hip_runtime.h>
#include <stdint.h>

typedef __attribute__((ext_vector_type(8))) short short8;
typedef __attribute__((ext_vector_type(4))) float floatx4;
typedef __attribute__((ext_vector_type(16))) float floatx16;

__device__ __forceinline__ float bf2f(unsigned short h) {
  union { unsigned int u; float f; } v; v.u = ((unsigned int)h) << 16; return v.f;
}
__device__ __forceinline__ unsigned short f2bf(float f) {
  union { float f; unsigned int u; } v; v.f = f;
  unsigned int r = v.u + 0x7fffu + ((v.u >> 16) & 1u);
  return (unsigned short)(r >> 16);
}

__device__ __forceinline__ void gll16(const void* g, void* l) {
  __builtin_amdgcn_global_load_lds((const __attribute__((address_space(1))) unsigned int*)g,
                                   (__attribute__((address_space(3))) unsigned int*)l, 16, 0, 0);
}

// XCD-aware block swizzle (T1): XCD k gets a contiguous run of work-ids. Bijective when nwg%8==0.
__device__ __forceinline__ int xcd_swz_id() {
  const int nx = gridDim.x;
  const int nwg = nx * gridDim.y;
  const int orig = blockIdx.y * nx + blockIdx.x;
  if ((nwg & 7) == 0) {
    const int q = nwg >> 3;
    return (orig & 7) * q + (orig >> 3);
  }
  return orig;
}

// DPP row_ror:K — VALU pipe.
template <int K>
__device__ __forceinline__ float rorf(float x) {
  return __int_as_float(__builtin_amdgcn_update_dpp(0, __float_as_int(x), 0x120 + K, 0xF, 0xF, false));
}
__device__ __forceinline__ float grpsum16(float v) {
  v += rorf<1>(v); v += rorf<2>(v); v += rorf<4>(v); v += rorf<8>(v);
  return v;
}
__device__ __forceinline__ float swz16(float x) {
  return __int_as_float(__builtin_amdgcn_ds_swizzle(__float_as_int(x), 0x401F));
}

// ------------- weight transpose+convert: in f32 (K,N) -> out bf16 (N,K) -------------
__global__ __launch_bounds__(256) void transpose_kern(const float* __restrict__ in,
                                                      unsigned short* __restrict__ out,
                                                      int K, int N) {
  __shared__ float tile[32][33];
  const int tx = threadIdx.x & 31, ty = threadIdx.x >> 5;
  const int n0 = blockIdx.x * 32, k0 = blockIdx.y * 32;
#pragma unroll
  for (int i = 0; i < 4; ++i)
    tile[ty + 8 * i][tx] = in[(size_t)(k0 + ty + 8 * i) * N + n0 + tx];
  __syncthreads();
#pragma unroll
  for (int i = 0; i < 4; ++i)
    out[(size_t)(n0 + ty + 8 * i) * K + k0 + tx] = f2bf(tile[tx][ty + 8 * i]);
}

// ------------- LayerNorm, one WAVE per row (4 rows/block): f32 or bf16 in -> bf16 out -------------
template <int BF16IN>
__global__ __launch_bounds__(256) void ln_kern(const void* __restrict__ xv,
                                               const float* __restrict__ g,
                                               const float* __restrict__ b,
                                               unsigned short* __restrict__ out,
                                               int tokenBase, int scatter) {
  const int l = threadIdx.x & 63, wv = threadIdx.x >> 6;
  const int t = tokenBase + blockIdx.x * 4 + wv;
  const int c0 = l * 8;
  float v[8];
  if (BF16IN) {
    short8 u = *(const short8*)((const unsigned short*)xv + (size_t)t * 512 + c0);
#pragma unroll
    for (int j = 0; j < 8; ++j) v[j] = bf2f((unsigned short)u[j]);
  } else {
    const float* xr = (const float*)xv + (size_t)t * 512 + c0;
    floatx4 a = *(const floatx4*)xr;
    floatx4 a2 = *(const floatx4*)(xr + 4);
#pragma unroll
    for (int j = 0; j < 4; ++j) { v[j] = a[j]; v[4 + j] = a2[j]; }
  }
  float s = 0.0f, s2 = 0.0f;
#pragma unroll
  for (int j = 0; j < 8; ++j) { s += v[j]; s2 += v[j] * v[j]; }
#pragma unroll
  for (int off = 32; off; off >>= 1) {
    s += __shfl_xor(s, off, 64);
    s2 += __shfl_xor(s2, off, 64);
  }
  const float mean = s * (1.0f / 512.0f);
  const float var = s2 * (1.0f / 512.0f) - mean * mean;
  const float rstd = rsqrtf(var + 1e-5f);
  const floatx4 g0 = *(const floatx4*)(g + c0), g1 = *(const floatx4*)(g + c0 + 4);
  const floatx4 b0 = *(const floatx4*)(b + c0), b1 = *(const floatx4*)(b + c0 + 4);
  short8 o;
#pragma unroll
  for (int j = 0; j < 4; ++j) {
    o[j]     = (short)f2bf((v[j] - mean) * rstd * g0[j] + b0[j]);
    o[4 + j] = (short)f2bf((v[4 + j] - mean) * rstd * g1[j] + b1[j]);
  }
  int orow;
  if (scatter) {
    const int bb = t >> 12, rem = t & 4095, h = rem >> 6, w = rem & 63;
    const int hp = (h + 60) & 63, wp = (w + 60) & 63;
    const int wh = hp >> 3, i = hp & 7, ww = wp >> 3, j = wp & 7;
    const int rg = ((bb << 6) + (wh << 3) + ww) * 64 + (i << 3) + j;
    orow = rg - tokenBase;
  } else {
    orow = t - tokenBase;
  }
  *(short8*)(out + (size_t)orow * 512 + c0) = o;
}

// ------------- 128² GEMM (fallback path, R16/R18-proven structure): fused epilogues -------------
template <int EPI>
__global__ __launch_bounds__(256) void gemm_bt(const unsigned short* __restrict__ A,
                                               const unsigned short* __restrict__ Bt,
                                               const float* __restrict__ bias,
                                               void* __restrict__ outv,
                                               const void* __restrict__ resv,
                                               int M, int N, int K, int rowBase) {
  __shared__ unsigned short As[2][128][64];
  __shared__ unsigned short Bs[2][128][64];
  const int tid = threadIdx.x;
  const int l = tid & 63, wv = tid >> 6;
  const int wm = wv >> 1, wn = wv & 1;
  const int id = xcd_swz_id();
  const int bm = (id / gridDim.x) * 128, bn = (id % gridDim.x) * 128;

  floatx4 acc[4][4];
#pragma unroll
  for (int i = 0; i < 4; ++i)
#pragma unroll
    for (int j = 0; j < 4; ++j) acc[i][j] = {0.0f, 0.0f, 0.0f, 0.0f};

  const int srow = l >> 3;
  const int sslot = ((l & 7) ^ (l >> 3)) * 8;
  const unsigned short* Abase = A + (size_t)(bm + srow) * K + sslot;
  const unsigned short* Bbase = Bt + (size_t)(bn + srow) * K + sslot;

#define STAGE(bb, k0)                                                        \
  {                                                                          \
    _Pragma("unroll")                                                        \
    for (int tt = 0; tt < 4; ++tt) {                                         \
      const int r = wv * 32 + tt * 8;                                        \
      gll16(Abase + (size_t)r * K + (k0), &As[bb][r][0]);                    \
      gll16(Bbase + (size_t)r * K + (k0), &Bs[bb][r][0]);                    \
    }                                                                        \
  }

  STAGE(0, 0);
  __syncthreads();

  const int ntl = K >> 6;
  int cur = 0;
#pragma unroll 1
  for (int t = 0; t < ntl; ++t) {
    if (t + 1 < ntl) STAGE(cur ^ 1, (t + 1) * 64);
    __builtin_amdgcn_s_setprio(1);
#pragma unroll
    for (int kh = 0; kh < 2; ++kh) {
      const int rslot = ((kh * 4 + (l >> 4)) ^ (l & 7)) * 8;
      short8 af[4], bfr[4];
#pragma unroll
      for (int mt = 0; mt < 4; ++mt)
        af[mt] = *(const short8*)&As[cur][wm * 64 + mt * 16 + (l & 15)][rslot];
#pragma unroll
      for (int nt2 = 0; nt2 < 4; ++nt2)
        bfr[nt2] = *(const short8*)&Bs[cur][wn * 64 + nt2 * 16 + (l & 15)][rslot];
#pragma unroll
      for (int mt = 0; mt < 4; ++mt)
#pragma unroll
        for (int nt2 = 0; nt2 < 4; ++nt2)
          acc[mt][nt2] = __builtin_amdgcn_mfma_f32_16x16x32_bf16(af[mt], bfr[nt2], acc[mt][nt2], 0, 0, 0);
    }
    __builtin_amdgcn_s_setprio(0);
    if (t + 1 < ntl) {
      __syncthreads();
      cur ^= 1;
    }
  }
#undef STAGE

#pragma unroll
  for (int mt = 0; mt < 4; ++mt) {
#pragma unroll
    for (int nt2 = 0; nt2 < 4; ++nt2) {
      const int gcol = bn + wn * 64 + nt2 * 16 + (l & 15);
      const float bv = bias[gcol];
#pragma unroll
      for (int r = 0; r < 4; ++r) {
        const int grow = bm + wm * 64 + mt * 16 + (l >> 4) * 4 + r;
        float v = acc[mt][nt2][r] + bv;
        if (EPI == 1) {
          const float t2 = v * (1.5957691216057308f + 0.071354816222f * v * v);
          v = v * (1.0f / (1.0f + __expf(-t2)));
        }
        if (EPI == 2) {
          const int rg = rowBase + grow;
          const int bw = rg >> 6, n = rg & 63;
          const int bb = bw >> 6, wi = bw & 63;
          const int i = n >> 3, j = n & 7;
          const int hp = ((wi >> 3) << 3) + i;
          const int wp = ((wi & 7) << 3) + j;
          const int h = (hp + 4) & 63, w = (wp + 4) & 63;
          const size_t t = (size_t)((bb << 12) + (h << 6) + w);
          ((unsigned short*)outv)[t * 512 + gcol] = f2bf(v + ((const float*)resv)[t * 512 + gcol]);
        } else if (EPI == 3) {
          ((float*)outv)[(size_t)grow * 512 + gcol] =
              v + bf2f(((const unsigned short*)resv)[(size_t)grow * 512 + gcol]);
        } else {
          ((unsigned short*)outv)[(size_t)grow * (size_t)N + gcol] = f2bf(v);
        }
      }
    }
  }
}

// ------------- 256² GEMM, 32x32x16 MFMA (8 waves, per-wave 128x64): qkv(0), fc1(1), proj(2), fc2(3) ---
// C/D layout (HW-verified): col = lane&31, row = (reg&3) + 8*(reg>>2) + 4*(lane>>5)
template <int EPI>
__global__ __launch_bounds__(512) void gemm256(const unsigned short* __restrict__ A,
                                               const unsigned short* __restrict__ Bt,
                                               const float* __restrict__ bias,
                                               void* __restrict__ outv,
                                               const void* __restrict__ resv,
                                               int M, int N, int K, int rowBase) {
  __shared__ unsigned short As[2][256][64];
  __shared__ unsigned short Bs[2][256][64];
  const int tid = threadIdx.x;
  const int l = tid & 63, wid = tid >> 6;
  const int wm = wid >> 2, wn = wid & 3;
  const int id = xcd_swz_id();
  const int bm = (id / gridDim.x) * 256, bn = (id % gridDim.x) * 256;

  floatx16 acc[4][2];
#pragma unroll
  for (int i = 0; i < 4; ++i)
#pragma unroll
    for (int j = 0; j < 2; ++j)
#pragma unroll
      for (int r = 0; r < 16; ++r) acc[i][j][r] = 0.0f;

  const int srow = tid >> 3;
  const int sslot = ((tid & 7) ^ (srow & 7)) * 8;
  const unsigned short* Ab = A + (size_t)(bm + srow) * K + sslot;
  const unsigned short* Bb = Bt + (size_t)(bn + srow) * K + sslot;
  const int ldsbase = wid * 8;

#define STG256(bb, k0)                                                          \
  {                                                                             \
    _Pragma("unroll")                                                           \
    for (int tt = 0; tt < 4; ++tt) {                                            \
      gll16(Ab + (size_t)(tt * 64) * K + (k0), &As[bb][tt * 64 + ldsbase][0]);  \
      gll16(Bb + (size_t)(tt * 64) * K + (k0), &Bs[bb][tt * 64 + ldsbase][0]);  \
    }                                                                           \
  }

  STG256(0, 0);
  __syncthreads();

  const int ntl = K >> 6;
  int cur = 0;
#pragma unroll 1
  for (int t = 0; t < ntl; ++t) {
    if (t + 1 < ntl) STG256(cur ^ 1, (t + 1) * 64);
    __builtin_amdgcn_s_setprio(1);
#pragma unroll
    for (int ks = 0; ks < 4; ++ks) {            // 4 k-steps of K=16
      const int rslot = ((ks * 2 + (l >> 5)) ^ (l & 7)) * 8;
      short8 af[4], bfr[2];
#pragma unroll
      for (int mt = 0; mt < 4; ++mt)
        af[mt] = *(const short8*)&As[cur][wm * 128 + mt * 32 + (l & 31)][rslot];
#pragma unroll
      for (int nt2 = 0; nt2 < 2; ++nt2)
        bfr[nt2] = *(const short8*)&Bs[cur][wn * 64 + nt2 * 32 + (l & 31)][rslot];
#pragma unroll
      for (int mt = 0; mt < 4; ++mt)
#pragma unroll
        for (int nt2 = 0; nt2 < 2; ++nt2)
          acc[mt][nt2] = __builtin_amdgcn_mfma_f32_32x32x16_bf16(af[mt], bfr[nt2], acc[mt][nt2], 0, 0, 0);
    }
    __builtin_amdgcn_s_setprio(0);
    if (t + 1 < ntl) {
      __syncthreads();
      cur ^= 1;
    }
  }
#undef STG256

#pragma unroll
  for (int mt = 0; mt < 4; ++mt) {
#pragma unroll
    for (int nt2 = 0; nt2 < 2; ++nt2) {
      const int gcol = bn + wn * 64 + nt2 * 32 + (l & 31);
      const float bv = bias[gcol];
#pragma unroll
      for (int r = 0; r < 16; ++r) {
        const int grow = bm + wm * 128 + mt * 32 + (r & 3) + 8 * (r >> 2) + 4 * (l >> 5);
        float v = acc[mt][nt2][r] + bv;
        if (EPI == 1) {
          const float t2 = v * (1.5957691216057308f + 0.071354816222f * v * v);
          v = v * (1.0f / (1.0f + __expf(-t2)));
        }
        if (EPI == 2) {
          const int rg = rowBase + grow;
          const int bw = rg >> 6, n = rg & 63;
          const int bb = bw >> 6, wi = bw & 63;
          const int i = n >> 3, j = n & 7;
          const int hp = ((wi >> 3) << 3) + i;
          const int wp = ((wi & 7) << 3) + j;
          const int h = (hp + 4) & 63, w = (wp + 4) & 63;
          const size_t t = (size_t)((bb << 12) + (h << 6) + w);
          ((unsigned short*)outv)[t * 512 + gcol] = f2bf(v + ((const float*)resv)[t * 512 + gcol]);
        } else if (EPI == 3) {
          ((float*)outv)[(size_t)grow * 512 + gcol] =
              v + bf2f(((const unsigned short*)resv)[(size_t)grow * 512 + gcol]);
        } else {
          ((unsigned short*)outv)[(size_t)grow * (size_t)N + gcol] = f2bf(v);
        }
      }
    }
  }
}

// ------------- attention per (window, head), 8 waves: QK^T + bias, top-48 radix, P@V ----
__global__ __launch_bounds__(512) void attn_kern(const unsigned short* __restrict__ qkv,
                                                 const float* __restrict__ relb,
                                                 unsigned short* __restrict__ attnout) {
  __shared__ float Ss[64][66];
  __shared__ unsigned short VT[32][66];
  __shared__ float biasL[240];

  const int u = blockIdx.x;
  const int bwl = u >> 4, head = u & 15;
  const int tid = threadIdx.x;
  const int l = tid & 63, w = tid >> 6;   // 8 waves

  if (tid < 256) {
    const int row = tid >> 2, d0 = (tid & 3) * 8;
    short8 v8 = *(const short8*)(qkv + (size_t)(bwl * 64 + row) * 1536 + 1024 + head * 32 + d0);
#pragma unroll
    for (int j = 0; j < 8; ++j) VT[d0 + j][row] = (unsigned short)v8[j];
  } else if (tid < 256 + 225) {
    biasL[tid - 256] = relb[(tid - 256) * 16 + head];
  }
  __syncthreads();

  {
    const int rb = w >> 1, ch = w & 1;
    short8 a = *(const short8*)(qkv + (size_t)(bwl * 64 + rb * 16 + (l & 15)) * 1536 +
                                head * 32 + (l >> 4) * 8);
    const int n0 = rb * 16 + (l >> 4) * 4;
    const int m0 = ch * 32 + (l & 15);
    const int ibase = ((n0 >> 3) - (m0 >> 3) + 7) * 15 + ((n0 & 7) - (m0 & 7) + 7);
#pragma unroll
    for (int nt2 = 0; nt2 < 2; ++nt2) {
      short8 bfr = *(const short8*)(qkv + (size_t)(bwl * 64 + ch * 32 + nt2 * 16 + (l & 15)) * 1536 +
                                    512 + head * 32 + (l >> 4) * 8);
      floatx4 z = {0.0f, 0.0f, 0.0f, 0.0f};
      floatx4 d = __builtin_amdgcn_mfma_f32_16x16x32_bf16(a, bfr, z, 0, 0, 0);
#pragma unroll
      for (int r = 0; r < 4; ++r)
        Ss[n0 + r][m0 + nt2 * 16] = fmaf(d[r], 0.17677669529663689f, biasL[ibase + r - 30 * nt2]);
    }
  }
  __syncthreads();

  // top-48 + softmax: wave w owns rows w*8..w*8+7 (ballot-radix threshold — proven fastest form)
  float* srow_base = &Ss[w * 8][0];
#pragma unroll 1
  for (int rr = 0; rr < 8; ++rr) {
    const float own = srow_base[rr * 66 + l];
    const unsigned int uo = __float_as_uint(own);
    const unsigned int mapped = uo ^ ((unsigned int)((int)uo >> 31) | 0x80000000u);
    unsigned int p = 0;
#pragma unroll
    for (int b = 31; b >= 0; --b) {
      const unsigned int cand = p | (1u << b);
      const int c = __popcll(__ballot(mapped >= cand));
      if (c >= 48) {
        p = cand;
        if (c == 48) break;   // exactly 48 kept — threshold found
      }
    }
    const float tf = __uint_as_float((p & 0x80000000u) ? (p ^ 0x80000000u) : ~p);
    const float e = (mapped >= p) ? __expf(own - tf) : 0.0f;
    float zs = grpsum16(e);
    zs += swz16(zs);
    zs += __shfl_xor(zs, 32, 64);
    ((unsigned short*)(srow_base + rr * 66))[l] = f2bf(e * __builtin_amdgcn_rcpf(zs));
  }
  __syncthreads();

  {
    const int rb = w >> 1, cb = w & 1;
    floatx4 acc = {0.0f, 0.0f, 0.0f, 0.0f};
#pragma unroll
    for (int kh = 0; kh < 2; ++kh) {
      short8 pa = *(const short8*)((const unsigned short*)&Ss[rb * 16 + (l & 15)][0] +
                                   kh * 32 + (l >> 4) * 8);
      short8 vb = *(const short8*)&VT[cb * 16 + (l & 15)][kh * 32 + (l >> 4) * 8];
      acc = __builtin_amdgcn_mfma_f32_16x16x32_bf16(pa, vb, acc, 0, 0, 0);
    }
#pragma unroll
    for (int r = 0; r < 4; ++r) {
      const int n = rb * 16 + (l >> 4) * 4 + r;
      const int dcol = cb * 16 + (l & 15);
      attnout[(size_t)(bwl * 64 + n) * 512 + head * 32 + dcol] = f2bf(acc[r]);
    }
  }
}

// ---------------- launcher ----------------
extern "C" void kernel_launch(void* const* d_in, const int* in_sizes, int n_in,
                              void* d_out, int out_size, void* d_ws, size_t ws_size,
                              hipStream_t stream) {
  (void)in_sizes; (void)n_in; (void)out_size;
  const float* x      = (const float*)d_in[0];
  const float* n1g    = (const float*)d_in[1];
  const float* n1b    = (const float*)d_in[2];
  const float* qkv_w  = (const float*)d_in[3];
  const float* qkv_b  = (const float*)d_in[4];
  const float* relb   = (const float*)d_in[5];
  const float* proj_w = (const float*)d_in[6];
  const float* proj_b = (const float*)d_in[7];
  const float* n2g    = (const float*)d_in[8];
  const float* n2b    = (const float*)d_in[9];
  const float* fc1_w  = (const float*)d_in[10];
  const float* fc1_b  = (const float*)d_in[11];
  const float* fc2_w  = (const float*)d_in[12];
  const float* fc2_b  = (const float*)d_in[13];
  float* outp = (float*)d_out;

  unsigned short* qkvT  = (unsigned short*)d_ws;
  unsigned short* projT = qkvT + 1536 * 512;
  unsigned short* fc1T  = projT + 512 * 512;
  unsigned short* fc2T  = fc1T + 2048 * 512;
  const size_t wbytes = (size_t)(1536 * 512 + 512 * 512 + 2048 * 512 + 512 * 2048) * 2;
  unsigned short* x2bf = (unsigned short*)((char*)d_ws + wbytes);
  const size_t x2bytes = (size_t)65536 * 512 * 2;
  size_t rem = (ws_size > wbytes + x2bytes) ? ws_size - wbytes - x2bytes : 0;
  int R = (int)(rem / 5120);
  R = (R / 4096) * 4096;
  if (R > 65536) R = 65536;   // single-pass when ws permits (512 MiB does: 405 MB needed)
  if (R < 4096) R = 4096;
  const int nch = 65536 / R;
  unsigned short* bufA = x2bf + (size_t)65536 * 512;
  unsigned short* bufB = bufA + (size_t)R * 512;

  transpose_kern<<<dim3(1536 / 32, 512 / 32), 256, 0, stream>>>(qkv_w, qkvT, 512, 1536);
  transpose_kern<<<dim3(512 / 32, 512 / 32), 256, 0, stream>>>(proj_w, projT, 512, 512);
  transpose_kern<<<dim3(2048 / 32, 512 / 32), 256, 0, stream>>>(fc1_w, fc1T, 512, 2048);
  transpose_kern<<<dim3(512 / 32, 2048 / 32), 256, 0, stream>>>(fc2_w, fc2T, 2048, 512);

  for (int cb = 0; cb < nch; ++cb) {
    ln_kern<0><<<R / 4, 256, 0, stream>>>(x, n1g, n1b, bufA, cb * R, 1);
    if ((R & 255) == 0) {
      gemm256<0><<<dim3(6, R / 256), 512, 0, stream>>>(bufA, qkvT, qkv_b, bufB, nullptr,
                                                       R, 1536, 512, 0);
    } else {
      gemm_bt<0><<<dim3(12, R / 128), 256, 0, stream>>>(bufA, qkvT, qkv_b, bufB, nullptr,
                                                        R, 1536, 512, 0);
    }
    attn_kern<<<(R / 64) * 16, 512, 0, stream>>>(bufB, relb, bufA);
    if ((R & 255) == 0) {
      gemm256<2><<<dim3(2, R / 256), 512, 0, stream>>>(bufA, projT, proj_b, x2bf, x,
                                                       R, 512, 512, cb * R);
    } else {
      gemm_bt<2><<<dim3(4, R / 128), 256, 0, stream>>>(bufA, projT, proj_b, x2bf, x,
                                                       R, 512, 512, cb * R);
    }
    ln_kern<1><<<R / 4, 256, 0, stream>>>(x2bf, n2g, n2b, bufA, cb * R, 0);
    if ((R & 255) == 0) {
      gemm256<1><<<dim3(8, R / 256), 512, 0, stream>>>(bufA, fc1T, fc1_b, bufB, nullptr,
                                                       R, 2048, 512, 0);
      gemm256<3><<<dim3(2, R / 256), 512, 0, stream>>>(bufB, fc2T, fc2_b,
                                                       outp + (size_t)cb * R * 512,
                                                       x2bf + (size_t)cb * R * 512,
                                                       R, 512, 2048, 0);
    } else {
      gemm_bt<1><<<dim3(16, R / 128), 256, 0, stream>>>(bufA, fc1T, fc1_b, bufB, nullptr,
                                                        R, 2048, 512, 0);
      gemm_bt<3><<<dim3(4, R / 128), 256, 0, stream>>>(bufB, fc2T, fc2_b,
                                                       outp + (size_t)cb * R * 512,
                                                       x2bf + (size_t)cb * R * 512,
                                                       R, 512, 2048, 0);
    }
  }
}